// Round 1
// baseline (8634.204 us; speedup 1.0000x reference)
//
#include <hip/hip_runtime.h>
#include <hip/hip_bf16.h>
#include <cmath>

#define D 768
#define LAYERS 12
#define NH 12
#define DKH 64
#define DF 3072
#define VOCAB 50257
#define EPS 1e-5f

// ---------------------------------------------------------------- embedding
__global__ __launch_bounds__(256) void embed_kernel(
    const int* __restrict__ ids, const float* __restrict__ tok,
    const float* __restrict__ pos, float* __restrict__ x, int S) {
  int row = blockIdx.x;           // b*S + s
  int s = row % S;
  int id = ids[row];
  const float* te = tok + (size_t)id * D;
  const float* pe = pos + (size_t)s * D;
  float* xr = x + (size_t)row * D;
  for (int c = threadIdx.x; c < D; c += 256)
    xr[c] = te[c] + pe[c];
}

// ---------------------------------------------------------------- layernorm
__global__ __launch_bounds__(256) void ln_kernel(
    const float* __restrict__ x, const float* __restrict__ g,
    const float* __restrict__ b, float* __restrict__ out) {
  __shared__ float red[8];
  int row = blockIdx.x;
  const float* xr = x + (size_t)row * D;
  int t = threadIdx.x;
  float v0 = xr[t], v1 = xr[t + 256], v2 = xr[t + 512];
  float s  = v0 + v1 + v2;
  float sq = v0 * v0 + v1 * v1 + v2 * v2;
#pragma unroll
  for (int off = 32; off > 0; off >>= 1) {
    s  += __shfl_xor(s, off);
    sq += __shfl_xor(sq, off);
  }
  if ((t & 63) == 0) { red[t >> 6] = s; red[4 + (t >> 6)] = sq; }
  __syncthreads();
  s  = red[0] + red[1] + red[2] + red[3];
  sq = red[4] + red[5] + red[6] + red[7];
  float mean = s * (1.f / 768.f);
  float var  = sq * (1.f / 768.f) - mean * mean;
  float rs = rsqrtf(var + EPS);
  float* orow = out + (size_t)row * D;
  orow[t]       = (v0 - mean) * rs * g[t]       + b[t];
  orow[t + 256] = (v1 - mean) * rs * g[t + 256] + b[t + 256];
  orow[t + 512] = (v2 - mean) * rs * g[t + 512] + b[t + 512];
}

// ---------------------------------------------------------------- GEMM (fp32)
// C[M,N] = A[M,K] @ B[K,N] + bias (+gelu | +residual). 64x64x64 tiles.
__device__ __forceinline__ float gelu_exact(float x) {
  return 0.5f * x * (1.0f + erff(x * 0.70710678118654752f));
}

template <int EPI>   // 0: bias, 1: bias+gelu, 2: bias+residual
__global__ __launch_bounds__(256) void gemm_kernel(
    const float* __restrict__ A, const float* __restrict__ B,
    const float* __restrict__ bias, const float* res, float* C,
    int M, int N, int K) {
  __shared__ float As[64][68];   // [k][m], padded: conflict-free transpose store
  __shared__ float Bs[64][64];   // [k][n]
  const int n0 = blockIdx.x * 64, m0 = blockIdx.y * 64;
  const int tid = threadIdx.x;
  const int tm = (tid / 16) * 4, tn = (tid % 16) * 4;
  float acc[4][4];
#pragma unroll
  for (int i = 0; i < 4; i++)
#pragma unroll
    for (int j = 0; j < 4; j++) acc[i][j] = 0.f;

  for (int k0 = 0; k0 < K; k0 += 64) {
#pragma unroll
    for (int i = 0; i < 4; i++) {
      int f = tid + i * 256;          // 1024 float4s per 64x64 tile
      int r = f >> 4, c4 = f & 15;
      float4 av = *(const float4*)(A + (size_t)(m0 + r) * K + k0 + c4 * 4);
      As[c4 * 4 + 0][r] = av.x;
      As[c4 * 4 + 1][r] = av.y;
      As[c4 * 4 + 2][r] = av.z;
      As[c4 * 4 + 3][r] = av.w;
      *(float4*)&Bs[r][c4 * 4] =
          *(const float4*)(B + (size_t)(k0 + r) * N + n0 + c4 * 4);
    }
    __syncthreads();
#pragma unroll 16
    for (int kk = 0; kk < 64; kk++) {
      float4 a = *(const float4*)&As[kk][tm];
      float4 bv = *(const float4*)&Bs[kk][tn];
      float ar[4] = {a.x, a.y, a.z, a.w};
      float br[4] = {bv.x, bv.y, bv.z, bv.w};
#pragma unroll
      for (int i = 0; i < 4; i++)
#pragma unroll
        for (int j = 0; j < 4; j++)
          acc[i][j] = fmaf(ar[i], br[j], acc[i][j]);
    }
    __syncthreads();
  }

  float bb[4];
#pragma unroll
  for (int j = 0; j < 4; j++) bb[j] = bias[n0 + tn + j];
#pragma unroll
  for (int i = 0; i < 4; i++) {
    size_t off = (size_t)(m0 + tm + i) * N + n0 + tn;
    float o[4];
#pragma unroll
    for (int j = 0; j < 4; j++) {
      float val = acc[i][j] + bb[j];
      if (EPI == 1) val = gelu_exact(val);
      if (EPI == 2) val += res[off + j];
      o[j] = val;
    }
    *(float4*)(C + off) = make_float4(o[0], o[1], o[2], o[3]);
  }
}

// ------------------------------------------------- GEMM, B transposed (logits)
// C[M,N] = A[M,K] @ Bt[N,K]^T   (N = VOCAB, guarded)
__global__ __launch_bounds__(256) void gemm_bt_kernel(
    const float* __restrict__ A, const float* __restrict__ Bt,
    float* __restrict__ C, int M, int N, int K) {
  __shared__ float As[64][68];
  __shared__ float Bs[64][68];
  const int n0 = blockIdx.x * 64, m0 = blockIdx.y * 64;
  const int tid = threadIdx.x;
  const int tm = (tid / 16) * 4, tn = (tid % 16) * 4;
  float acc[4][4];
#pragma unroll
  for (int i = 0; i < 4; i++)
#pragma unroll
    for (int j = 0; j < 4; j++) acc[i][j] = 0.f;

  for (int k0 = 0; k0 < K; k0 += 64) {
#pragma unroll
    for (int i = 0; i < 4; i++) {
      int f = tid + i * 256;
      int r = f >> 4, c4 = f & 15;
      float4 av = *(const float4*)(A + (size_t)(m0 + r) * K + k0 + c4 * 4);
      As[c4 * 4 + 0][r] = av.x;
      As[c4 * 4 + 1][r] = av.y;
      As[c4 * 4 + 2][r] = av.z;
      As[c4 * 4 + 3][r] = av.w;
      float4 bv = make_float4(0.f, 0.f, 0.f, 0.f);
      if (n0 + r < N)
        bv = *(const float4*)(Bt + (size_t)(n0 + r) * K + k0 + c4 * 4);
      Bs[c4 * 4 + 0][r] = bv.x;
      Bs[c4 * 4 + 1][r] = bv.y;
      Bs[c4 * 4 + 2][r] = bv.z;
      Bs[c4 * 4 + 3][r] = bv.w;
    }
    __syncthreads();
#pragma unroll 16
    for (int kk = 0; kk < 64; kk++) {
      float4 a = *(const float4*)&As[kk][tm];
      float4 bv = *(const float4*)&Bs[kk][tn];
      float ar[4] = {a.x, a.y, a.z, a.w};
      float br[4] = {bv.x, bv.y, bv.z, bv.w};
#pragma unroll
      for (int i = 0; i < 4; i++)
#pragma unroll
        for (int j = 0; j < 4; j++)
          acc[i][j] = fmaf(ar[i], br[j], acc[i][j]);
    }
    __syncthreads();
  }
#pragma unroll
  for (int i = 0; i < 4; i++) {
    size_t off = (size_t)(m0 + tm + i) * N;
#pragma unroll
    for (int j = 0; j < 4; j++) {
      int n = n0 + tn + j;
      if (n < N) C[off + n] = acc[i][j];
    }
  }
}

// ---------------------------------------------------------------- attention
// One block per (b, head, 64 q-rows). Flash-style online softmax, fp32.
__global__ __launch_bounds__(256) void attn_kernel(
    const float* __restrict__ qg, const float* __restrict__ kg,
    const float* __restrict__ vg, float* __restrict__ og, int S) {
  __shared__ float qs[64][65];   // padded: row-indexed reads -> 2-way (free)
  __shared__ float ks[64][64];   // broadcast reads -> no pad needed
  __shared__ float vs[64][64];
  __shared__ float ss[64][65];
  __shared__ float redm[4][64];
  __shared__ float redl[4][64];
  const int qt = blockIdx.x, h = blockIdx.y, b = blockIdx.z;
  const int tid = threadIdx.x;
  const int r = tid & 63;        // q-row within tile
  const int w = tid >> 6;        // wave: owns output cols w*16..w*16+15
  const int q0 = qt * 64;
  const size_t base = ((size_t)b * S) * D + (size_t)h * DKH;

#pragma unroll
  for (int i = 0; i < 4; i++) {
    int f = tid + i * 256;
    int rr = f >> 4, c4 = f & 15;
    float4 qv = *(const float4*)(qg + base + (size_t)(q0 + rr) * D + c4 * 4);
    qs[rr][c4 * 4 + 0] = qv.x; qs[rr][c4 * 4 + 1] = qv.y;
    qs[rr][c4 * 4 + 2] = qv.z; qs[rr][c4 * 4 + 3] = qv.w;
  }

  float m = -INFINITY, l = 0.f;
  float acc[16];
#pragma unroll
  for (int j = 0; j < 16; j++) acc[j] = 0.f;

  for (int kt = 0; kt <= qt; kt++) {
    __syncthreads();             // protect ks/vs/ss/red from prev iteration
#pragma unroll
    for (int i = 0; i < 4; i++) {
      int f = tid + i * 256;
      int rr = f >> 4, c4 = f & 15;
      *(float4*)&ks[rr][c4 * 4] =
          *(const float4*)(kg + base + (size_t)(kt * 64 + rr) * D + c4 * 4);
      *(float4*)&vs[rr][c4 * 4] =
          *(const float4*)(vg + base + (size_t)(kt * 64 + rr) * D + c4 * 4);
    }
    __syncthreads();

    float sc[16];
#pragma unroll
    for (int j = 0; j < 16; j++) sc[j] = 0.f;
#pragma unroll 8
    for (int d = 0; d < 64; d++) {
      float qv = qs[r][d];
#pragma unroll
      for (int j = 0; j < 16; j++)
        sc[j] = fmaf(qv, ks[w * 16 + j][d], sc[j]);
    }
    const int gq = q0 + r;
    float tmax = -INFINITY;
#pragma unroll
    for (int j = 0; j < 16; j++) {
      sc[j] *= 0.125f;                              // 1/sqrt(64)
      if (kt * 64 + w * 16 + j > gq) sc[j] = -INFINITY;  // causal
      tmax = fmaxf(tmax, sc[j]);
    }
    redm[w][r] = tmax;
    __syncthreads();
    float mnew = fmaxf(m, fmaxf(fmaxf(redm[0][r], redm[1][r]),
                                fmaxf(redm[2][r], redm[3][r])));
    float alpha = expf(m - mnew);
    float psum = 0.f;
#pragma unroll
    for (int j = 0; j < 16; j++) {
      float p = expf(sc[j] - mnew);
      ss[r][w * 16 + j] = p;
      psum += p;
    }
    redl[w][r] = psum;
    __syncthreads();
    l = l * alpha + redl[0][r] + redl[1][r] + redl[2][r] + redl[3][r];
    m = mnew;
#pragma unroll
    for (int j = 0; j < 16; j++) acc[j] *= alpha;
#pragma unroll 8
    for (int c = 0; c < 64; c++) {
      float p = ss[r][c];
#pragma unroll
      for (int j = 0; j < 16; j++)
        acc[j] = fmaf(p, vs[c][w * 16 + j], acc[j]);
    }
  }
  float inv = 1.f / l;
#pragma unroll
  for (int j = 0; j < 16; j++)
    og[base + (size_t)(q0 + r) * D + w * 16 + j] = acc[j] * inv;
}

// ---------------------------------------------------------------- launch
extern "C" void kernel_launch(void* const* d_in, const int* in_sizes, int n_in,
                              void* d_out, int out_size, void* d_ws,
                              size_t ws_size, hipStream_t stream) {
  const int*   ids  = (const int*)d_in[0];
  const float* tok  = (const float*)d_in[1];
  const float* pos  = (const float*)d_in[2];
  const float* wq   = (const float*)d_in[3];
  const float* bq   = (const float*)d_in[4];
  const float* wk   = (const float*)d_in[5];
  const float* bk   = (const float*)d_in[6];
  const float* wv   = (const float*)d_in[7];
  const float* bv   = (const float*)d_in[8];
  const float* wo   = (const float*)d_in[9];
  const float* bo   = (const float*)d_in[10];
  const float* w1   = (const float*)d_in[11];
  const float* b1   = (const float*)d_in[12];
  const float* w2   = (const float*)d_in[13];
  const float* b2   = (const float*)d_in[14];
  const float* ln1g = (const float*)d_in[15];
  const float* ln1b = (const float*)d_in[16];
  const float* ln2g = (const float*)d_in[17];
  const float* ln2b = (const float*)d_in[18];
  const float* lnfg = (const float*)d_in[19];
  const float* lnfb = (const float*)d_in[20];

  const int S = 512;
  const int M = in_sizes[0];          // B*S = 1024
  const int B = M / S;

  float* ws = (float*)d_ws;
  float* x  = ws;                     // [M,D]
  float* hb = x  + (size_t)M * D;     // [M,D]   LN output
  float* qb = hb + (size_t)M * D;     // [M,D]
  float* kb = qb + (size_t)M * D;
  float* vb = kb + (size_t)M * D;
  float* ob = vb + (size_t)M * D;     // attention output
  float* fb = ob + (size_t)M * D;     // [M,DF]

  embed_kernel<<<M, 256, 0, stream>>>(ids, tok, pos, x, S);

  const dim3 gD(D / 64, M / 64);      // (12,16)
  const dim3 gF(DF / 64, M / 64);     // (48,16)
  const dim3 gA(S / 64, NH, B);       // (8,12,2)

  for (int l = 0; l < LAYERS; l++) {
    const float* Wq = wq + (size_t)l * D * D;
    const float* Wk = wk + (size_t)l * D * D;
    const float* Wv = wv + (size_t)l * D * D;
    const float* Wo = wo + (size_t)l * D * D;
    const float* W1 = w1 + (size_t)l * D * DF;
    const float* W2 = w2 + (size_t)l * DF * D;

    ln_kernel<<<M, 256, 0, stream>>>(x, ln1g + l * D, ln1b + l * D, hb);
    gemm_kernel<0><<<gD, 256, 0, stream>>>(hb, Wq, bq + l * D, nullptr, qb, M, D, D);
    gemm_kernel<0><<<gD, 256, 0, stream>>>(hb, Wk, bk + l * D, nullptr, kb, M, D, D);
    gemm_kernel<0><<<gD, 256, 0, stream>>>(hb, Wv, bv + l * D, nullptr, vb, M, D, D);
    attn_kernel<<<gA, 256, 0, stream>>>(qb, kb, vb, ob, S);
    gemm_kernel<2><<<gD, 256, 0, stream>>>(ob, Wo, bo + l * D, x, x, M, D, D);
    ln_kernel<<<M, 256, 0, stream>>>(x, ln2g + l * D, ln2b + l * D, hb);
    gemm_kernel<1><<<gF, 256, 0, stream>>>(hb, W1, b1 + l * DF, nullptr, fb, M, DF, D);
    gemm_kernel<2><<<gD, 256, 0, stream>>>(fb, W2, b2 + l * D, x, x, M, D, DF);
  }

  ln_kernel<<<M, 256, 0, stream>>>(x, lnfg, lnfb, hb);
  const dim3 gL((VOCAB + 63) / 64, M / 64);   // (786,16)
  gemm_bt_kernel<<<gL, 256, 0, stream>>>(hb, tok, (float*)d_out, M, VOCAB, D);
}

// Round 2
// 2868.769 us; speedup vs baseline: 3.0097x; 3.0097x over previous
//
#include <hip/hip_runtime.h>
#include <hip/hip_bf16.h>
#include <cmath>
#include <cstdint>

#define D 768
#define LAYERS 12
#define NH 12
#define DKH 64
#define DF 3072
#define VOCAB 50257
#define EPS 1e-5f

typedef float f32x4 __attribute__((ext_vector_type(4)));
typedef __bf16 b16x8 __attribute__((ext_vector_type(8)));
typedef __hip_bfloat16 bf16;

__device__ __forceinline__ float gelu_exact(float x) {
  return 0.5f * x * (1.0f + erff(x * 0.70710678118654752f));
}

// async 16B global->LDS. lds must be wave-uniform; g is per-lane.
__device__ __forceinline__ void gll16(const void* g, void* lds) {
  __builtin_amdgcn_global_load_lds(
      (const __attribute__((address_space(1))) unsigned int*)(unsigned long long)(uintptr_t)g,
      (__attribute__((address_space(3))) unsigned int*)(unsigned int)(uintptr_t)lds,
      16, 0, 0);
}

__device__ __forceinline__ f32x4 mfma16(b16x8 a, b16x8 b, f32x4 c) {
  return __builtin_amdgcn_mfma_f32_16x16x32_bf16(a, b, c, 0, 0, 0);
}

// ---------------------------------------------------------------- embedding
__global__ __launch_bounds__(256) void embed_kernel(
    const int* __restrict__ ids, const float* __restrict__ tok,
    const float* __restrict__ pos, float* __restrict__ x, int S) {
  int row = blockIdx.x;
  int s = row % S;
  int id = ids[row];
  const float* te = tok + (size_t)id * D;
  const float* pe = pos + (size_t)s * D;
  float* xr = x + (size_t)row * D;
  for (int c = threadIdx.x; c < D; c += 256)
    xr[c] = te[c] + pe[c];
}

// ---------------------------------------------------------------- layernorm
template <typename OutT>
__global__ __launch_bounds__(256) void ln_kernel(
    const float* __restrict__ x, const float* __restrict__ g,
    const float* __restrict__ b, OutT* __restrict__ out) {
  __shared__ float red[8];
  int row = blockIdx.x;
  const float* xr = x + (size_t)row * D;
  int t = threadIdx.x;
  float v0 = xr[t], v1 = xr[t + 256], v2 = xr[t + 512];
  float s  = v0 + v1 + v2;
  float sq = v0 * v0 + v1 * v1 + v2 * v2;
#pragma unroll
  for (int off = 32; off > 0; off >>= 1) {
    s  += __shfl_xor(s, off);
    sq += __shfl_xor(sq, off);
  }
  if ((t & 63) == 0) { red[t >> 6] = s; red[4 + (t >> 6)] = sq; }
  __syncthreads();
  s  = red[0] + red[1] + red[2] + red[3];
  sq = red[4] + red[5] + red[6] + red[7];
  float mean = s * (1.f / 768.f);
  float var  = sq * (1.f / 768.f) - mean * mean;
  float rs = rsqrtf(var + EPS);
  OutT* orow = out + (size_t)row * D;
  orow[t]       = (OutT)((v0 - mean) * rs * g[t]       + b[t]);
  orow[t + 256] = (OutT)((v1 - mean) * rs * g[t + 256] + b[t + 256]);
  orow[t + 512] = (OutT)((v2 - mean) * rs * g[t + 512] + b[t + 512]);
}

// ---------------------------------------------------------------- converts
__global__ __launch_bounds__(256) void cvt_bf16_kernel(
    const float* __restrict__ in, bf16* __restrict__ out, int n4) {
  int stride = gridDim.x * 256;
  for (int i = blockIdx.x * 256 + threadIdx.x; i < n4; i += stride) {
    float4 v = ((const float4*)in)[i];
    bf16 a = __float2bfloat16(v.x), b = __float2bfloat16(v.y);
    bf16 c = __float2bfloat16(v.z), d = __float2bfloat16(v.w);
    unsigned int lo = *(unsigned short*)&a | ((unsigned int)*(unsigned short*)&b << 16);
    unsigned int hi = *(unsigned short*)&c | ((unsigned int)*(unsigned short*)&d << 16);
    *(uint2*)(out + (size_t)i * 4) = make_uint2(lo, hi);
  }
}

// in [R,C] fp32 -> out [C,R] bf16, blockIdx.z = tensor index
__global__ __launch_bounds__(256) void transpose_cvt_kernel(
    const float* __restrict__ in, bf16* __restrict__ out, int R, int C) {
  __shared__ float t[64][65];
  const size_t tsz = (size_t)R * C;
  const float* ip = in + tsz * blockIdx.z;
  bf16* op = out + tsz * blockIdx.z;
  const int r0 = blockIdx.y * 64, c0 = blockIdx.x * 64;
  const int tid = threadIdx.x;
  const int cr = tid >> 4;
  const int cc = (tid & 15) * 4;
#pragma unroll
  for (int i = 0; i < 4; i++) {
    int r = cr + i * 16;
    float4 v = *(const float4*)(ip + (size_t)(r0 + r) * C + c0 + cc);
    t[r][cc] = v.x; t[r][cc + 1] = v.y; t[r][cc + 2] = v.z; t[r][cc + 3] = v.w;
  }
  __syncthreads();
  const int rr = (tid & 7) * 8;
#pragma unroll
  for (int p = 0; p < 2; p++) {
    int c = (tid >> 3) + p * 32;
    unsigned int pk[4];
#pragma unroll
    for (int j = 0; j < 4; j++) {
      bf16 lo = __float2bfloat16(t[rr + 2 * j][c]);
      bf16 hi = __float2bfloat16(t[rr + 2 * j + 1][c]);
      pk[j] = (unsigned int)(*(unsigned short*)&lo) |
              ((unsigned int)(*(unsigned short*)&hi) << 16);
    }
    *(uint4*)(op + (size_t)(c0 + c) * R + r0 + rr) =
        make_uint4(pk[0], pk[1], pk[2], pk[3]);
  }
}

// ------------------------------------------------------------- bf16 GEMM core
// A [M,K] bf16 row-major; Bt [N,K] bf16 row-major (weights pre-transposed).
// LDS tiles [rows][64] bf16 (128B rows), XOR-swizzled: data for k-chunk c of
// row r sits at chunk (c ^ (r&7)). Staged via global_load_lds with the
// inverse-swizzled per-lane GLOBAL source (rule: linear dest + pre-swz src).
template <int BM, int BN, bool NG>
__device__ __forceinline__ void gemm_core(
    const bf16* __restrict__ A, const bf16* __restrict__ Bt,
    int m0, int n0, int K, int Nrows, char* smem,
    f32x4 (&acc)[BM / 32][BN / 32], int tid) {
  const int lane = tid & 63, w = tid >> 6;
  const int wm = (w >> 1) * (BM / 2), wn = (w & 1) * (BN / 2);
  char* As = smem;
  char* Bs = smem + BM * 128;
  const int lr = lane >> 3;            // row within 8-row group
  const int lc = (lane & 7) ^ lr;      // inverse-swizzled source k-chunk

  for (int k0 = 0; k0 < K; k0 += 64) {
    __syncthreads();
#pragma unroll
    for (int i = 0; i < BM / 32; i++) {
      int r0 = (i * 4 + w) * 8;
      gll16(A + (size_t)(m0 + r0 + lr) * K + k0 + lc * 8, As + r0 * 128);
    }
#pragma unroll
    for (int i = 0; i < BN / 32; i++) {
      int r0 = (i * 4 + w) * 8;
      int nrow = n0 + r0 + lr;
      if (NG) nrow = nrow < Nrows ? nrow : Nrows - 1;
      gll16(Bt + (size_t)nrow * K + k0 + lc * 8, Bs + r0 * 128);
    }
    __syncthreads();
#pragma unroll
    for (int h = 0; h < 2; h++) {
      b16x8 af[BM / 32], bfv[BN / 32];
#pragma unroll
      for (int i = 0; i < BM / 32; i++) {
        int row = wm + i * 16 + (lane & 15);
        uint32_t off = (uint32_t)(row * 128) +
                       (((h << 6) + ((lane >> 4) << 4)) ^ ((row & 7) << 4));
        af[i] = *(const b16x8*)(As + off);
      }
#pragma unroll
      for (int j = 0; j < BN / 32; j++) {
        int row = wn + j * 16 + (lane & 15);
        uint32_t off = (uint32_t)(row * 128) +
                       (((h << 6) + ((lane >> 4) << 4)) ^ ((row & 7) << 4));
        bfv[j] = *(const b16x8*)(Bs + off);
      }
#pragma unroll
      for (int i = 0; i < BM / 32; i++)
#pragma unroll
        for (int j = 0; j < BN / 32; j++)
          acc[i][j] = mfma16(af[i], bfv[j], acc[i][j]);
    }
  }
}

// ---------------------------------------------------------- bf16 GEMM kernels
// fused QKV: grid.x = 18 (3 segments x 6 n-blocks of 128), grid.y = M/128
__global__ __launch_bounds__(256) void gemm_qkv_kernel(
    const bf16* __restrict__ A, const bf16* __restrict__ wqt,
    const bf16* __restrict__ wkt, const bf16* __restrict__ wvt,
    const float* __restrict__ bq, const float* __restrict__ bk,
    const float* __restrict__ bv, float* __restrict__ qo,
    float* __restrict__ ko, float* __restrict__ vo, int K) {
  __shared__ __align__(16) char smem[2 * 128 * 128];
  const int tid = threadIdx.x;
  const int nb = blockIdx.x;
  const int seg = nb / 6;
  const int n0 = (nb - seg * 6) * 128;
  const int m0 = blockIdx.y * 128;
  const bf16* Bt = seg == 0 ? wqt : (seg == 1 ? wkt : wvt);
  const float* bias = seg == 0 ? bq : (seg == 1 ? bk : bv);
  float* out = seg == 0 ? qo : (seg == 1 ? ko : vo);
  f32x4 acc[4][4] = {};
  gemm_core<128, 128, false>(A, Bt, m0, n0, K, 0, smem, acc, tid);
  const int lane = tid & 63, w = tid >> 6;
  const int rb = m0 + (w >> 1) * 64 + ((lane >> 4) << 2);
  const int cb = n0 + (w & 1) * 64 + (lane & 15);
#pragma unroll
  for (int j = 0; j < 4; j++) {
    int col = cb + j * 16;
    float bb = bias[col];
#pragma unroll
    for (int i = 0; i < 4; i++)
#pragma unroll
      for (int r = 0; r < 4; r++)
        out[(size_t)(rb + i * 16 + r) * D + col] = acc[i][j][r] + bb;
  }
}

// 64x64 tile, +bias +residual -> fp32 (out-proj, FF2)
__global__ __launch_bounds__(256) void gemm64_res_kernel(
    const bf16* __restrict__ A, const bf16* __restrict__ Bt,
    const float* __restrict__ bias, const float* __restrict__ res,
    float* __restrict__ C, int Nd, int K) {
  __shared__ __align__(16) char smem[2 * 64 * 128];
  const int tid = threadIdx.x;
  const int m0 = blockIdx.y * 64, n0 = blockIdx.x * 64;
  f32x4 acc[2][2] = {};
  gemm_core<64, 64, false>(A, Bt, m0, n0, K, 0, smem, acc, tid);
  const int lane = tid & 63, w = tid >> 6;
  const int rb = m0 + (w >> 1) * 32 + ((lane >> 4) << 2);
  const int cb = n0 + (w & 1) * 32 + (lane & 15);
#pragma unroll
  for (int j = 0; j < 2; j++) {
    int col = cb + j * 16;
    float bb = bias[col];
#pragma unroll
    for (int i = 0; i < 2; i++)
#pragma unroll
      for (int r = 0; r < 4; r++) {
        size_t off = (size_t)(rb + i * 16 + r) * Nd + col;
        C[off] = acc[i][j][r] + bb + res[off];
      }
  }
}

// 128x128 tile, gelu(bias) -> bf16 (FF1)
__global__ __launch_bounds__(256) void gemm128_gelu_kernel(
    const bf16* __restrict__ A, const bf16* __restrict__ Bt,
    const float* __restrict__ bias, bf16* __restrict__ C, int Nd, int K) {
  __shared__ __align__(16) char smem[2 * 128 * 128];
  const int tid = threadIdx.x;
  const int m0 = blockIdx.y * 128, n0 = blockIdx.x * 128;
  f32x4 acc[4][4] = {};
  gemm_core<128, 128, false>(A, Bt, m0, n0, K, 0, smem, acc, tid);
  const int lane = tid & 63, w = tid >> 6;
  const int rb = m0 + (w >> 1) * 64 + ((lane >> 4) << 2);
  const int cb = n0 + (w & 1) * 64 + (lane & 15);
#pragma unroll
  for (int j = 0; j < 4; j++) {
    int col = cb + j * 16;
    float bb = bias[col];
#pragma unroll
    for (int i = 0; i < 4; i++)
#pragma unroll
      for (int r = 0; r < 4; r++)
        C[(size_t)(rb + i * 16 + r) * Nd + col] =
            __float2bfloat16(gelu_exact(acc[i][j][r] + bb));
  }
}

// 128x128 tile, plain -> fp32, N-guarded (LM head)
__global__ __launch_bounds__(256) void gemm128_head_kernel(
    const bf16* __restrict__ A, const bf16* __restrict__ Bt,
    float* __restrict__ C, int Nd, int K) {
  __shared__ __align__(16) char smem[2 * 128 * 128];
  const int tid = threadIdx.x;
  const int m0 = blockIdx.y * 128, n0 = blockIdx.x * 128;
  f32x4 acc[4][4] = {};
  gemm_core<128, 128, true>(A, Bt, m0, n0, K, Nd, smem, acc, tid);
  const int lane = tid & 63, w = tid >> 6;
  const int rb = m0 + (w >> 1) * 64 + ((lane >> 4) << 2);
  const int cb = n0 + (w & 1) * 64 + (lane & 15);
#pragma unroll
  for (int j = 0; j < 4; j++) {
    int col = cb + j * 16;
    if (col < Nd) {
#pragma unroll
      for (int i = 0; i < 4; i++)
#pragma unroll
        for (int r = 0; r < 4; r++)
          C[(size_t)(rb + i * 16 + r) * Nd + col] = acc[i][j][r];
    }
  }
}

// ---------------------------------------------------------------- attention
template <typename OutT>
__global__ __launch_bounds__(256) void attn_kernel(
    const float* __restrict__ qg, const float* __restrict__ kg,
    const float* __restrict__ vg, OutT* __restrict__ og, int S) {
  __shared__ float qs[64][65];
  __shared__ float ks[64][64];
  __shared__ float vs[64][64];
  __shared__ float ss[64][65];
  __shared__ float redm[4][64];
  __shared__ float redl[4][64];
  const int qt = blockIdx.x, h = blockIdx.y, b = blockIdx.z;
  const int tid = threadIdx.x;
  const int r = tid & 63;
  const int w = tid >> 6;
  const int q0 = qt * 64;
  const size_t base = ((size_t)b * S) * D + (size_t)h * DKH;

#pragma unroll
  for (int i = 0; i < 4; i++) {
    int f = tid + i * 256;
    int rr = f >> 4, c4 = f & 15;
    float4 qv = *(const float4*)(qg + base + (size_t)(q0 + rr) * D + c4 * 4);
    qs[rr][c4 * 4 + 0] = qv.x; qs[rr][c4 * 4 + 1] = qv.y;
    qs[rr][c4 * 4 + 2] = qv.z; qs[rr][c4 * 4 + 3] = qv.w;
  }

  float m = -INFINITY, l = 0.f;
  float acc[16];
#pragma unroll
  for (int j = 0; j < 16; j++) acc[j] = 0.f;

  for (int kt = 0; kt <= qt; kt++) {
    __syncthreads();
#pragma unroll
    for (int i = 0; i < 4; i++) {
      int f = tid + i * 256;
      int rr = f >> 4, c4 = f & 15;
      *(float4*)&ks[rr][c4 * 4] =
          *(const float4*)(kg + base + (size_t)(kt * 64 + rr) * D + c4 * 4);
      *(float4*)&vs[rr][c4 * 4] =
          *(const float4*)(vg + base + (size_t)(kt * 64 + rr) * D + c4 * 4);
    }
    __syncthreads();

    float sc[16];
#pragma unroll
    for (int j = 0; j < 16; j++) sc[j] = 0.f;
#pragma unroll 8
    for (int d = 0; d < 64; d++) {
      float qv = qs[r][d];
#pragma unroll
      for (int j = 0; j < 16; j++)
        sc[j] = fmaf(qv, ks[w * 16 + j][d], sc[j]);
    }
    const int gq = q0 + r;
    float tmax = -INFINITY;
#pragma unroll
    for (int j = 0; j < 16; j++) {
      sc[j] *= 0.125f;
      if (kt * 64 + w * 16 + j > gq) sc[j] = -INFINITY;
      tmax = fmaxf(tmax, sc[j]);
    }
    redm[w][r] = tmax;
    __syncthreads();
    float mnew = fmaxf(m, fmaxf(fmaxf(redm[0][r], redm[1][r]),
                                fmaxf(redm[2][r], redm[3][r])));
    float alpha = expf(m - mnew);
    float psum = 0.f;
#pragma unroll
    for (int j = 0; j < 16; j++) {
      float p = expf(sc[j] - mnew);
      ss[r][w * 16 + j] = p;
      psum += p;
    }
    redl[w][r] = psum;
    __syncthreads();
    l = l * alpha + redl[0][r] + redl[1][r] + redl[2][r] + redl[3][r];
    m = mnew;
#pragma unroll
    for (int j = 0; j < 16; j++) acc[j] *= alpha;
#pragma unroll 8
    for (int c = 0; c < 64; c++) {
      float p = ss[r][c];
#pragma unroll
      for (int j = 0; j < 16; j++)
        acc[j] = fmaf(p, vs[c][w * 16 + j], acc[j]);
    }
  }
  float inv = 1.f / l;
#pragma unroll
  for (int j = 0; j < 16; j++)
    og[base + (size_t)(q0 + r) * D + w * 16 + j] = (OutT)(acc[j] * inv);
}

// =================================================== fp32 fallback GEMMs
template <int EPI>
__global__ __launch_bounds__(256) void gemm_f32_kernel(
    const float* __restrict__ A, const float* __restrict__ B,
    const float* __restrict__ bias, const float* res, float* C,
    int M, int N, int K) {
  __shared__ float As[64][68];
  __shared__ float Bs[64][64];
  const int n0 = blockIdx.x * 64, m0 = blockIdx.y * 64;
  const int tid = threadIdx.x;
  const int tm = (tid / 16) * 4, tn = (tid % 16) * 4;
  float acc[4][4];
#pragma unroll
  for (int i = 0; i < 4; i++)
#pragma unroll
    for (int j = 0; j < 4; j++) acc[i][j] = 0.f;
  for (int k0 = 0; k0 < K; k0 += 64) {
#pragma unroll
    for (int i = 0; i < 4; i++) {
      int f = tid + i * 256;
      int r = f >> 4, c4 = f & 15;
      float4 av = *(const float4*)(A + (size_t)(m0 + r) * K + k0 + c4 * 4);
      As[c4 * 4 + 0][r] = av.x; As[c4 * 4 + 1][r] = av.y;
      As[c4 * 4 + 2][r] = av.z; As[c4 * 4 + 3][r] = av.w;
      *(float4*)&Bs[r][c4 * 4] =
          *(const float4*)(B + (size_t)(k0 + r) * N + n0 + c4 * 4);
    }
    __syncthreads();
#pragma unroll 16
    for (int kk = 0; kk < 64; kk++) {
      float4 a = *(const float4*)&As[kk][tm];
      float4 bv = *(const float4*)&Bs[kk][tn];
      float ar[4] = {a.x, a.y, a.z, a.w};
      float br[4] = {bv.x, bv.y, bv.z, bv.w};
#pragma unroll
      for (int i = 0; i < 4; i++)
#pragma unroll
        for (int j = 0; j < 4; j++)
          acc[i][j] = fmaf(ar[i], br[j], acc[i][j]);
    }
    __syncthreads();
  }
  float bb[4];
#pragma unroll
  for (int j = 0; j < 4; j++) bb[j] = bias[n0 + tn + j];
#pragma unroll
  for (int i = 0; i < 4; i++) {
    size_t off = (size_t)(m0 + tm + i) * N + n0 + tn;
    float o[4];
#pragma unroll
    for (int j = 0; j < 4; j++) {
      float val = acc[i][j] + bb[j];
      if (EPI == 1) val = gelu_exact(val);
      if (EPI == 2) val += res[off + j];
      o[j] = val;
    }
    *(float4*)(C + off) = make_float4(o[0], o[1], o[2], o[3]);
  }
}

__global__ __launch_bounds__(256) void gemm_bt_f32_kernel(
    const float* __restrict__ A, const float* __restrict__ Bt,
    float* __restrict__ C, int M, int N, int K) {
  __shared__ float As[64][68];
  __shared__ float Bs[64][68];
  const int n0 = blockIdx.x * 64, m0 = blockIdx.y * 64;
  const int tid = threadIdx.x;
  const int tm = (tid / 16) * 4, tn = (tid % 16) * 4;
  float acc[4][4];
#pragma unroll
  for (int i = 0; i < 4; i++)
#pragma unroll
    for (int j = 0; j < 4; j++) acc[i][j] = 0.f;
  for (int k0 = 0; k0 < K; k0 += 64) {
#pragma unroll
    for (int i = 0; i < 4; i++) {
      int f = tid + i * 256;
      int r = f >> 4, c4 = f & 15;
      float4 av = *(const float4*)(A + (size_t)(m0 + r) * K + k0 + c4 * 4);
      As[c4 * 4 + 0][r] = av.x; As[c4 * 4 + 1][r] = av.y;
      As[c4 * 4 + 2][r] = av.z; As[c4 * 4 + 3][r] = av.w;
      float4 bv = make_float4(0.f, 0.f, 0.f, 0.f);
      if (n0 + r < N)
        bv = *(const float4*)(Bt + (size_t)(n0 + r) * K + k0 + c4 * 4);
      Bs[c4 * 4 + 0][r] = bv.x; Bs[c4 * 4 + 1][r] = bv.y;
      Bs[c4 * 4 + 2][r] = bv.z; Bs[c4 * 4 + 3][r] = bv.w;
    }
    __syncthreads();
#pragma unroll 16
    for (int kk = 0; kk < 64; kk++) {
      float4 a = *(const float4*)&As[kk][tm];
      float4 bv = *(const float4*)&Bs[kk][tn];
      float ar[4] = {a.x, a.y, a.z, a.w};
      float br[4] = {bv.x, bv.y, bv.z, bv.w};
#pragma unroll
      for (int i = 0; i < 4; i++)
#pragma unroll
        for (int j = 0; j < 4; j++)
          acc[i][j] = fmaf(ar[i], br[j], acc[i][j]);
    }
    __syncthreads();
  }
#pragma unroll
  for (int i = 0; i < 4; i++) {
    size_t off = (size_t)(m0 + tm + i) * N;
#pragma unroll
    for (int j = 0; j < 4; j++) {
      int n = n0 + tn + j;
      if (n < N) C[off + n] = acc[i][j];
    }
  }
}

// ---------------------------------------------------------------- launch
extern "C" void kernel_launch(void* const* d_in, const int* in_sizes, int n_in,
                              void* d_out, int out_size, void* d_ws,
                              size_t ws_size, hipStream_t stream) {
  const int*   ids  = (const int*)d_in[0];
  const float* tok  = (const float*)d_in[1];
  const float* pos  = (const float*)d_in[2];
  const float* wq   = (const float*)d_in[3];
  const float* bq   = (const float*)d_in[4];
  const float* wk   = (const float*)d_in[5];
  const float* bk   = (const float*)d_in[6];
  const float* wv   = (const float*)d_in[7];
  const float* bv   = (const float*)d_in[8];
  const float* wo   = (const float*)d_in[9];
  const float* bo   = (const float*)d_in[10];
  const float* w1   = (const float*)d_in[11];
  const float* b1   = (const float*)d_in[12];
  const float* w2   = (const float*)d_in[13];
  const float* b2   = (const float*)d_in[14];
  const float* ln1g = (const float*)d_in[15];
  const float* ln1b = (const float*)d_in[16];
  const float* ln2g = (const float*)d_in[17];
  const float* ln2b = (const float*)d_in[18];
  const float* lnfg = (const float*)d_in[19];
  const float* lnfb = (const float*)d_in[20];

  const int S = 512;
  const int M = in_sizes[0];
  const int B = M / S;

  // ---- bf16-path workspace carve
  size_t off = 0;
  auto carve = [&](size_t bytes) {
    size_t o = off;
    off += (bytes + 255) & ~(size_t)255;
    return o;
  };
  const size_t o_x  = carve((size_t)M * D * 4);
  const size_t o_q  = carve((size_t)M * D * 4);
  const size_t o_k  = carve((size_t)M * D * 4);
  const size_t o_v  = carve((size_t)M * D * 4);
  const size_t o_h  = carve((size_t)M * D * 2);
  const size_t o_o  = carve((size_t)M * D * 2);
  const size_t o_f  = carve((size_t)M * DF * 2);
  const size_t o_wq = carve((size_t)LAYERS * D * D * 2);
  const size_t o_wk = carve((size_t)LAYERS * D * D * 2);
  const size_t o_wv = carve((size_t)LAYERS * D * D * 2);
  const size_t o_wo = carve((size_t)LAYERS * D * D * 2);
  const size_t o_w1 = carve((size_t)LAYERS * D * DF * 2);
  const size_t o_w2 = carve((size_t)LAYERS * DF * D * 2);
  const size_t o_tk = carve((size_t)VOCAB * D * 2);
  const size_t need = off;

  if (ws_size >= need) {
    char* wsb = (char*)d_ws;
    float* x   = (float*)(wsb + o_x);
    float* qb_ = (float*)(wsb + o_q);
    float* kb_ = (float*)(wsb + o_k);
    float* vb_ = (float*)(wsb + o_v);
    bf16*  hb  = (bf16*)(wsb + o_h);
    bf16*  ob  = (bf16*)(wsb + o_o);
    bf16*  fb  = (bf16*)(wsb + o_f);
    bf16*  wqt = (bf16*)(wsb + o_wq);
    bf16*  wkt = (bf16*)(wsb + o_wk);
    bf16*  wvt = (bf16*)(wsb + o_wv);
    bf16*  wot = (bf16*)(wsb + o_wo);
    bf16*  w1t = (bf16*)(wsb + o_w1);
    bf16*  w2t = (bf16*)(wsb + o_w2);
    bf16*  tkb = (bf16*)(wsb + o_tk);

    // weight conversion (every call; weights static per call)
    cvt_bf16_kernel<<<2048, 256, 0, stream>>>(tok, tkb, VOCAB * D / 4);
    const dim3 gT(12, 12, LAYERS);
    transpose_cvt_kernel<<<gT, 256, 0, stream>>>(wq, wqt, D, D);
    transpose_cvt_kernel<<<gT, 256, 0, stream>>>(wk, wkt, D, D);
    transpose_cvt_kernel<<<gT, 256, 0, stream>>>(wv, wvt, D, D);
    transpose_cvt_kernel<<<gT, 256, 0, stream>>>(wo, wot, D, D);
    transpose_cvt_kernel<<<dim3(DF / 64, 12, LAYERS), 256, 0, stream>>>(w1, w1t, D, DF);
    transpose_cvt_kernel<<<dim3(12, DF / 64, LAYERS), 256, 0, stream>>>(w2, w2t, DF, D);

    embed_kernel<<<M, 256, 0, stream>>>(ids, tok, pos, x, S);

    const dim3 gQKV(18, M / 128);
    const dim3 g64(D / 64, M / 64);
    const dim3 gFF1(DF / 128, M / 128);
    const dim3 gA(S / 64, NH, B);

    for (int l = 0; l < LAYERS; l++) {
      const size_t wofs = (size_t)l * D * D;
      ln_kernel<bf16><<<M, 256, 0, stream>>>(x, ln1g + l * D, ln1b + l * D, hb);
      gemm_qkv_kernel<<<gQKV, 256, 0, stream>>>(
          hb, wqt + wofs, wkt + wofs, wvt + wofs,
          bq + l * D, bk + l * D, bv + l * D, qb_, kb_, vb_, D);
      attn_kernel<bf16><<<gA, 256, 0, stream>>>(qb_, kb_, vb_, ob, S);
      gemm64_res_kernel<<<g64, 256, 0, stream>>>(
          ob, wot + wofs, bo + l * D, x, x, D, D);
      ln_kernel<bf16><<<M, 256, 0, stream>>>(x, ln2g + l * D, ln2b + l * D, hb);
      gemm128_gelu_kernel<<<gFF1, 256, 0, stream>>>(
          hb, w1t + (size_t)l * D * DF, b1 + (size_t)l * DF, fb, DF, D);
      gemm64_res_kernel<<<g64, 256, 0, stream>>>(
          fb, w2t + (size_t)l * DF * D, b2 + l * D, x, x, D, DF);
    }
    ln_kernel<bf16><<<M, 256, 0, stream>>>(x, lnfg, lnfb, hb);
    gemm128_head_kernel<<<dim3((VOCAB + 127) / 128, M / 128), 256, 0, stream>>>(
        hb, tkb, (float*)d_out, VOCAB, D);
    return;
  }

  // ---- fp32 fallback (previous round's proven path)
  float* ws = (float*)d_ws;
  float* x  = ws;
  float* hb = x  + (size_t)M * D;
  float* qb_ = hb + (size_t)M * D;
  float* kb_ = qb_ + (size_t)M * D;
  float* vb_ = kb_ + (size_t)M * D;
  float* ob = vb_ + (size_t)M * D;
  float* fb = ob + (size_t)M * D;

  embed_kernel<<<M, 256, 0, stream>>>(ids, tok, pos, x, S);
  const dim3 gD(D / 64, M / 64);
  const dim3 gF(DF / 64, M / 64);
  const dim3 gA(S / 64, NH, B);
  for (int l = 0; l < LAYERS; l++) {
    const float* Wq = wq + (size_t)l * D * D;
    const float* Wk = wk + (size_t)l * D * D;
    const float* Wv = wv + (size_t)l * D * D;
    const float* Wo = wo + (size_t)l * D * D;
    const float* W1 = w1 + (size_t)l * D * DF;
    const float* W2 = w2 + (size_t)l * DF * D;
    ln_kernel<float><<<M, 256, 0, stream>>>(x, ln1g + l * D, ln1b + l * D, hb);
    gemm_f32_kernel<0><<<gD, 256, 0, stream>>>(hb, Wq, bq + l * D, nullptr, qb_, M, D, D);
    gemm_f32_kernel<0><<<gD, 256, 0, stream>>>(hb, Wk, bk + l * D, nullptr, kb_, M, D, D);
    gemm_f32_kernel<0><<<gD, 256, 0, stream>>>(hb, Wv, bv + l * D, nullptr, vb_, M, D, D);
    attn_kernel<float><<<gA, 256, 0, stream>>>(qb_, kb_, vb_, ob, S);
    gemm_f32_kernel<2><<<gD, 256, 0, stream>>>(ob, Wo, bo + l * D, x, x, M, D, D);
    ln_kernel<float><<<M, 256, 0, stream>>>(x, ln2g + l * D, ln2b + l * D, hb);
    gemm_f32_kernel<1><<<gF, 256, 0, stream>>>(hb, W1, b1 + l * DF, nullptr, fb, M, DF, D);
    gemm_f32_kernel<2><<<gD, 256, 0, stream>>>(fb, W2, b2 + l * D, x, x, M, D, DF);
  }
  ln_kernel<float><<<M, 256, 0, stream>>>(x, lnfg, lnfb, hb);
  const dim3 gL((VOCAB + 63) / 64, M / 64);
  gemm_bt_f32_kernel<<<gL, 256, 0, stream>>>(hb, tok, (float*)d_out, M, VOCAB, D);
}